// Round 2
// baseline (1035.818 us; speedup 1.0000x reference)
//
#include <hip/hip_runtime.h>
#include <hip/hip_bf16.h>
#include <math.h>

#define B_ 1024
#define H_ 4
#define D_ 128
#define V_ 100000
#define VP_ 100096          // V padded to 782*128
#define M_ (B_*H_)          // 4096
#define EPS_ 1e-7f
#define LOG2E_ 1.4426950408889634f

typedef unsigned short ushort_t;
typedef __attribute__((ext_vector_type(4))) float f32x4;
typedef __attribute__((ext_vector_type(8))) short bf16x8;

__device__ __forceinline__ ushort_t f2bf(float f) {
    unsigned u = __float_as_uint(f);
    unsigned r = u + 0x7fffu + ((u >> 16) & 1u);   // RNE
    return (ushort_t)(r >> 16);
}
__device__ __forceinline__ float bf_lo(unsigned x) { return __uint_as_float(x << 16); }
__device__ __forceinline__ float bf_hi(unsigned x) { return __uint_as_float(x & 0xffff0000u); }

__device__ __forceinline__ void gload_lds16(const void* g, void* l) {
    __builtin_amdgcn_global_load_lds(
        (const __attribute__((address_space(1))) unsigned int*)g,
        (__attribute__((address_space(3))) unsigned int*)l,
        16, 0, 0);
}

// ---------------------------------------------------------------------------
// Kernel A: proj = tanh(inputs @ proj_mat.T) -> bf16 [4096,128]; pi = softmax(inputs @ mix_mat.T)
// ---------------------------------------------------------------------------
__global__ __launch_bounds__(512)
void proj_pi_kernel(const float* __restrict__ inputs, const float* __restrict__ proj_mat,
                    const float* __restrict__ mix_mat, ushort_t* __restrict__ Abf,
                    float* __restrict__ pi)
{
    __shared__ float xin[128];
    __shared__ float mixv[4];
    const int b = blockIdx.x, tid = threadIdx.x;
    if (tid < 128) xin[tid] = inputs[b * 128 + tid];
    __syncthreads();

    const float4* row = (const float4*)(proj_mat + tid * 128);
    float acc = 0.f;
#pragma unroll 8
    for (int k = 0; k < 32; ++k) {
        float4 m4 = row[k];
        acc += m4.x * xin[k*4+0] + m4.y * xin[k*4+1] + m4.z * xin[k*4+2] + m4.w * xin[k*4+3];
    }
    Abf[b * 512 + tid] = f2bf(tanhf(acc));

    if (tid < 4) {
        const float4* mrow = (const float4*)(mix_mat + tid * 128);
        float a2 = 0.f;
#pragma unroll 8
        for (int k = 0; k < 32; ++k) {
            float4 m4 = mrow[k];
            a2 += m4.x * xin[k*4+0] + m4.y * xin[k*4+1] + m4.z * xin[k*4+2] + m4.w * xin[k*4+3];
        }
        mixv[tid] = a2;
    }
    __syncthreads();
    if (tid < 4) {
        float m = fmaxf(fmaxf(mixv[0], mixv[1]), fmaxf(mixv[2], mixv[3]));
        float e0 = __expf(mixv[0]-m), e1 = __expf(mixv[1]-m), e2 = __expf(mixv[2]-m), e3 = __expf(mixv[3]-m);
        float s = e0 + e1 + e2 + e3;
        pi[b * 4 + tid] = __expf(mixv[tid]-m) / s;
    }
}

// ---------------------------------------------------------------------------
// Kernel B: embeddings fp32 -> bf16, pre-scaled by log2(e) so exp(logit) == exp2(acc)
// ---------------------------------------------------------------------------
__global__ __launch_bounds__(256)
void conv_kernel(const float* __restrict__ e, ushort_t* __restrict__ o, int n4)
{
    int i = blockIdx.x * 256 + threadIdx.x;
    if (i < n4) {
        float4 f = ((const float4*)e)[i];
        ushort4 u;
        u.x = f2bf(f.x * LOG2E_); u.y = f2bf(f.y * LOG2E_);
        u.z = f2bf(f.z * LOG2E_); u.w = f2bf(f.w * LOG2E_);
        ((ushort4*)o)[i] = u;
    }
}

// ---------------------------------------------------------------------------
// GEMM pass: A=[4096,128] bf16 (m=b*4+h), E=[100000,128] bf16*log2e.
//   S[b][v][h] = exp(logit) as bf16  (820 MB, layout gives coalesced ushort4 stores)
//   Z[m]     += sum_v exp(logit)     (fp32 butterfly + atomic)
// Tile: 128(m) x 128(n), K=128 in one LDS stage, 4 waves each 64x64.
// ---------------------------------------------------------------------------
__global__ __launch_bounds__(256, 2)
void gemm_s_kernel(const ushort_t* __restrict__ Abf, const ushort_t* __restrict__ Ebf,
                   ushort_t* __restrict__ S, float* __restrict__ Z)
{
    __shared__ ushort_t lds_a[128 * 128];
    __shared__ ushort_t lds_b[128 * 128];

    const int tid  = threadIdx.x;
    const int wave = tid >> 6;
    const int lane = tid & 63;
    const int q    = lane >> 4;
    const int r16  = lane & 15;
    const int m0   = blockIdx.x * 128;   // x = m-strip (32) fastest for emb L2 sharing
    const int v0   = blockIdx.y * 128;

    // --- staging: 8 iters x 4KB each tile; LDS slot (r,c) <- global chunk c^(r&7) ---
#pragma unroll
    for (int t = 0; t < 8; ++t) {
        int r  = t * 16 + (tid >> 4);
        int c  = tid & 15;
        int cs = c ^ (r & 7);
        unsigned loff = (unsigned)__builtin_amdgcn_readfirstlane(t * 4096 + (tid >> 6) * 1024);
        gload_lds16(Abf + (size_t)(m0 + r) * 128 + cs * 8, (char*)lds_a + loff);
        int vrow = v0 + r; if (vrow >= V_) vrow = V_ - 1;
        gload_lds16(Ebf + (size_t)vrow * 128 + cs * 8, (char*)lds_b + loff);
    }
    __syncthreads();

    const int wm = (wave >> 1) * 64;
    const int wn = (wave & 1) * 64;

    f32x4 acc[4][4];
#pragma unroll
    for (int mi = 0; mi < 4; ++mi)
#pragma unroll
        for (int ni = 0; ni < 4; ++ni)
            acc[mi][ni] = (f32x4)(0.f);

#pragma unroll
    for (int kk = 0; kk < 4; ++kk) {
        bf16x8 fa[4], fb[4];
        int chunk = kk * 4 + q;
#pragma unroll
        for (int mi = 0; mi < 4; ++mi) {
            int row = wm + mi * 16 + r16;
            int sc = chunk ^ (row & 7);
            fa[mi] = *(const bf16x8*)&lds_a[row * 128 + sc * 8];
        }
#pragma unroll
        for (int ni = 0; ni < 4; ++ni) {
            int row = wn + ni * 16 + r16;
            int sc = chunk ^ (row & 7);
            fb[ni] = *(const bf16x8*)&lds_b[row * 128 + sc * 8];
        }
#pragma unroll
        for (int mi = 0; mi < 4; ++mi)
#pragma unroll
            for (int ni = 0; ni < 4; ++ni)
                acc[mi][ni] = __builtin_amdgcn_mfma_f32_16x16x32_bf16(fa[mi], fb[ni], acc[mi][ni], 0, 0, 0);
    }

    // --- epilogue: exp2, store bf16 S, accumulate Z partials ---
    float zs[4][4];
#pragma unroll
    for (int mi = 0; mi < 4; ++mi)
#pragma unroll
        for (int h = 0; h < 4; ++h) zs[mi][h] = 0.f;

#pragma unroll
    for (int mi = 0; mi < 4; ++mi) {
        int bidx = (m0 + wm + mi * 16) / 4 + q;     // rows m0+wm+mi*16+q*4 .. +3 are heads of this b
#pragma unroll
        for (int ni = 0; ni < 4; ++ni) {
            int v = v0 + wn + ni * 16 + r16;
            f32x4 a = acc[mi][ni];
            float e0 = exp2f(a[0]), e1 = exp2f(a[1]), e2 = exp2f(a[2]), e3 = exp2f(a[3]);
            ushort4 s4;
            s4.x = f2bf(e0); s4.y = f2bf(e1); s4.z = f2bf(e2); s4.w = f2bf(e3);
            *(ushort4*)(S + ((size_t)bidx * VP_ + v) * 4) = s4;
            if (v < V_) {
                zs[mi][0] += e0; zs[mi][1] += e1; zs[mi][2] += e2; zs[mi][3] += e3;
            }
        }
    }
    // butterfly over lane bits 0..3 (the 16 v-columns)
#pragma unroll
    for (int msk = 1; msk < 16; msk <<= 1) {
#pragma unroll
        for (int mi = 0; mi < 4; ++mi)
#pragma unroll
            for (int h = 0; h < 4; ++h)
                zs[mi][h] += __shfl_xor(zs[mi][h], msk, 64);
    }
    int mi = r16 >> 2, h = r16 & 3;
    int midx = m0 + wm + mi * 16 + q * 4 + h;
    atomicAdd(&Z[midx], zs[mi][h]);
}

// ---------------------------------------------------------------------------
// Combine: probs[b][v] = sum_h (pi/Z)[b][h] * S[b][v][h]    (memory-bound)
// ---------------------------------------------------------------------------
__global__ __launch_bounds__(256)
void combine_kernel(const ushort_t* __restrict__ S, const float* __restrict__ pi,
                    const float* __restrict__ Z, float* __restrict__ probs)
{
    __shared__ float w[4];
    const int b = blockIdx.y;
    if (threadIdx.x < 4) w[threadIdx.x] = pi[b * 4 + threadIdx.x] / Z[b * 4 + threadIdx.x];
    __syncthreads();
    int v = (blockIdx.x * 256 + threadIdx.x) * 4;
    if (v >= V_) return;
    const uint4* sp = (const uint4*)(S + ((size_t)b * VP_ + v) * 4);
    uint4 sa = sp[0], sb = sp[1];
    float w0 = w[0], w1 = w[1], w2 = w[2], w3 = w[3];
    float4 r;
    r.x = w0 * bf_lo(sa.x) + w1 * bf_hi(sa.x) + w2 * bf_lo(sa.y) + w3 * bf_hi(sa.y);
    r.y = w0 * bf_lo(sa.z) + w1 * bf_hi(sa.z) + w2 * bf_lo(sa.w) + w3 * bf_hi(sa.w);
    r.z = w0 * bf_lo(sb.x) + w1 * bf_hi(sb.x) + w2 * bf_lo(sb.y) + w3 * bf_hi(sb.y);
    r.w = w0 * bf_lo(sb.z) + w1 * bf_hi(sb.z) + w2 * bf_lo(sb.w) + w3 * bf_hi(sb.w);
    *(float4*)(probs + (size_t)b * V_ + v) = r;
}

// ---------------------------------------------------------------------------
// Loss: -mean(log(clip(probs[b,label[b]], 1e-7, 1)))
// ---------------------------------------------------------------------------
__global__ __launch_bounds__(256)
void loss_kernel(const float* __restrict__ probs, const int* __restrict__ label,
                 float* __restrict__ out)
{
    __shared__ float red[256];
    int tid = threadIdx.x;
    float s = 0.f;
    for (int b = tid; b < B_; b += 256) {
        float p = probs[(size_t)b * V_ + label[b]];
        p = fminf(fmaxf(p, EPS_), 1.0f);
        s -= logf(p);
    }
    red[tid] = s;
    __syncthreads();
    for (int st = 128; st > 0; st >>= 1) {
        if (tid < st) red[tid] += red[tid + st];
        __syncthreads();
    }
    if (tid == 0) out[0] = red[0] / (float)B_;
}

// ---------------------------------------------------------------------------
extern "C" void kernel_launch(void* const* d_in, const int* in_sizes, int n_in,
                              void* d_out, int out_size, void* d_ws, size_t ws_size,
                              hipStream_t stream)
{
    const float* inputs   = (const float*)d_in[0];
    const int*   label    = (const int*)d_in[1];
    const float* emb      = (const float*)d_in[2];
    const float* proj_mat = (const float*)d_in[3];
    const float* mix_mat  = (const float*)d_in[4];
    float* out = (float*)d_out;

    char* ws = (char*)d_ws;
    ushort_t* emb_bf = (ushort_t*)ws;                       // 25,600,000 B
    ushort_t* A_bf   = (ushort_t*)(ws + 25600000);          //  1,048,576 B
    float*    pi     = (float*)(ws + 26648576);             //     16,384 B
    float*    Z      = (float*)(ws + 26664960);             //     16,384 B
    ushort_t* S      = (ushort_t*)(ws + 33554432);          // 819,986,432 B  [b][v][h] bf16

    conv_kernel<<<12500, 256, 0, stream>>>(emb, emb_bf, 3200000);
    proj_pi_kernel<<<1024, 512, 0, stream>>>(inputs, proj_mat, mix_mat, A_bf, pi);
    hipMemsetAsync(Z, 0, 4096 * sizeof(float), stream);

    dim3 g(32, 782);
    gemm_s_kernel<<<g, 256, 0, stream>>>(A_bf, emb_bf, S, Z);

    dim3 gc(98, 1024);
    combine_kernel<<<gc, 256, 0, stream>>>(S, pi, Z, out);

    loss_kernel<<<1, 256, 0, stream>>>(out, label, out + (size_t)B_ * V_);
}